// Round 2
// baseline (149.978 us; speedup 1.0000x reference)
//
#include <hip/hip_runtime.h>

static constexpr float F_IOU_TR   = 0.3f;
static constexpr float F_SCORE_TR = 0.0f;
static constexpr float F_EPS      = 1e-7f;

// Pack (score, idx) into a u64 whose unsigned order == (score asc, idx desc).
// Scores are >= 0 here, so the raw float bit pattern is monotone. ~idx makes
// the SMALLER index win on score ties (jnp.argmax = first occurrence).
__device__ __forceinline__ unsigned long long pack_cand(float score, unsigned int idx) {
    return ((unsigned long long)__float_as_uint(score) << 32) |
           (unsigned long long)(~idx);
}

__device__ __forceinline__ unsigned int unpack_idx(unsigned long long p) {
    return ~(unsigned int)(p & 0xFFFFFFFFull);
}

// Wave(64) shuffle reduce + 4-wave LDS reduce, then one atomicMax per class.
__device__ __forceinline__ void block_reduce_max2(unsigned long long b0,
                                                  unsigned long long b1,
                                                  unsigned long long* dst0,
                                                  unsigned long long* dst1) {
    __shared__ unsigned long long smem[4][2];
#pragma unroll
    for (int off = 32; off > 0; off >>= 1) {
        unsigned long long o0 = __shfl_down(b0, (unsigned)off, 64);
        unsigned long long o1 = __shfl_down(b1, (unsigned)off, 64);
        if (o0 > b0) b0 = o0;
        if (o1 > b1) b1 = o1;
    }
    const int wave = threadIdx.x >> 6;
    const int lane = threadIdx.x & 63;
    if (lane == 0) { smem[wave][0] = b0; smem[wave][1] = b1; }
    __syncthreads();
    if (threadIdx.x == 0) {
        unsigned long long m0 = smem[0][0], m1 = smem[0][1];
#pragma unroll
        for (int w = 1; w < 4; ++w) {
            if (smem[w][0] > m0) m0 = smem[w][0];
            if (smem[w][1] > m1) m1 = smem[w][1];
        }
        atomicMax(dst0, m0);
        atomicMax(dst1, m1);
    }
}

__device__ __forceinline__ float4 shfl_down1_f4(float4 x) {
    float4 r;
    r.x = __shfl_down(x.x, 1, 64);
    r.y = __shfl_down(x.y, 1, 64);
    r.z = __shfl_down(x.z, 1, 64);
    r.w = __shfl_down(x.w, 1, 64);
    return r;
}

// ---------------- Pass 1: per-class argmax of score ----------------
// Stream the array as float4[M], M = 2N, unit stride (fully coalesced).
// Even float4 index j holds (score, cls, x1, y1) of row j/2.
__device__ __forceinline__ void p1_handle(float4 q, int j,
                                          unsigned long long& b0,
                                          unsigned long long& b1) {
    if (!(j & 1) && q.x >= F_SCORE_TR) {
        unsigned long long p = pack_cand(q.x, (unsigned int)(j >> 1));
        if (q.y < 0.5f) { if (p > b0) b0 = p; }
        else            { if (p > b1) b1 = p; }
    }
}

__global__ __launch_bounds__(256) void nms_pass1(const float4* __restrict__ v, int M,
                                                 unsigned long long* __restrict__ ws) {
    unsigned long long b0 = 0ull, b1 = 0ull;
    const int stride = gridDim.x * blockDim.x;
    int j = blockIdx.x * blockDim.x + threadIdx.x;
    for (; j + 3 * stride < M; j += 4 * stride) {
        float4 a = v[j];
        float4 b = v[j + stride];
        float4 c = v[j + 2 * stride];
        float4 d = v[j + 3 * stride];
        p1_handle(a, j, b0, b1);
        p1_handle(b, j + stride, b0, b1);
        p1_handle(c, j + 2 * stride, b0, b1);
        p1_handle(d, j + 3 * stride, b0, b1);
    }
    for (; j < M; j += stride) p1_handle(v[j], j, b0, b1);
    block_reduce_max2(b0, b1, &ws[0], &ws[1]);
}

// ---------------- Pass 2: argmax among IoU-surviving boxes ----------------
// Same coalesced float4 stream; even lane pairs with odd neighbor via shfl.
// (stride and M are even => lane parity == index parity, and bounds conditions
// are identical within each even/odd lane pair, so the shuffle never splits.)
struct RefBoxes {
    float a0x, a0y, a0z, a1x, a1y, a1z, va;
    float c0x, c0y, c0z, c1x, c1y, c1z, vc;
};

__device__ __forceinline__ void p2_handle(float4 r0, int j, const RefBoxes& R,
                                          unsigned long long& b0,
                                          unsigned long long& b1) {
    float4 r1 = shfl_down1_f4(r0);   // odd lane's float4 = second half of row
    if (j & 1) return;               // odd lanes: data courier only
    const float score = r0.x;
    const bool  is1   = (r0.y >= 0.5f);

    const float blx = is1 ? R.c0x : R.a0x;
    const float bly = is1 ? R.c0y : R.a0y;
    const float blz = is1 ? R.c0z : R.a0z;
    const float bhx = is1 ? R.c1x : R.a1x;
    const float bhy = is1 ? R.c1y : R.a1y;
    const float bhz = is1 ? R.c1z : R.a1z;
    const float v1  = is1 ? R.vc  : R.va;

    const float lox = fmaxf(blx, r0.z);
    const float loy = fmaxf(bly, r0.w);
    const float loz = fmaxf(blz, r1.x);
    const float hix = fminf(bhx, r1.y);
    const float hiy = fminf(bhy, r1.z);
    const float hiz = fminf(bhz, r1.w);
    const float inter = (fmaxf(hix - lox, 0.0f) * fmaxf(hiy - loy, 0.0f)) * fmaxf(hiz - loz, 0.0f);
    const float v2    = ((r1.y - r0.z) * (r1.z - r0.w)) * (r1.w - r1.x);
    const float iou   = inter / (v1 + v2 - inter + F_EPS);

    if (score >= F_SCORE_TR && iou <= F_IOU_TR) {
        unsigned long long p = pack_cand(score, (unsigned int)(j >> 1));
        if (is1) { if (p > b1) b1 = p; }
        else     { if (p > b0) b0 = p; }
    }
}

__global__ __launch_bounds__(256) void nms_pass2(const float* __restrict__ res,
                                                 const float4* __restrict__ v, int M,
                                                 unsigned long long* __restrict__ ws) {
    // Decode each class's top box (written by pass 1; kernel boundary => visible).
    const unsigned int ia = unpack_idx(ws[0]);
    const unsigned int ic = unpack_idx(ws[1]);
    const float* pa = res + (size_t)ia * 8 + 2;
    const float* pc = res + (size_t)ic * 8 + 2;
    RefBoxes R;
    R.a0x = pa[0]; R.a0y = pa[1]; R.a0z = pa[2]; R.a1x = pa[3]; R.a1y = pa[4]; R.a1z = pa[5];
    R.c0x = pc[0]; R.c0y = pc[1]; R.c0z = pc[2]; R.c1x = pc[3]; R.c1y = pc[4]; R.c1z = pc[5];
    R.va = ((R.a1x - R.a0x) * (R.a1y - R.a0y)) * (R.a1z - R.a0z);
    R.vc = ((R.c1x - R.c0x) * (R.c1y - R.c0y)) * (R.c1z - R.c0z);

    unsigned long long b0 = 0ull, b1 = 0ull;
    const int stride = gridDim.x * blockDim.x;
    int j = blockIdx.x * blockDim.x + threadIdx.x;
    for (; j + 3 * stride < M; j += 4 * stride) {
        float4 a = v[j];
        float4 b = v[j + stride];
        float4 c = v[j + 2 * stride];
        float4 d = v[j + 3 * stride];
        p2_handle(a, j, R, b0, b1);
        p2_handle(b, j + stride, R, b0, b1);
        p2_handle(c, j + 2 * stride, R, b0, b1);
        p2_handle(d, j + 3 * stride, R, b0, b1);
    }
    for (; j < M; j += stride) p2_handle(v[j], j, R, b0, b1);
    block_reduce_max2(b0, b1, &ws[2], &ws[3]);
}

// Output rows: [c0:i0, c0:i1, c1:i0, c1:i1] x 8 cols = 32 floats.
__global__ void nms_write(const float* __restrict__ res,
                          const unsigned long long* __restrict__ ws,
                          float* __restrict__ out) {
    const int t = threadIdx.x;
    if (t >= 32) return;
    const int row  = t >> 3;
    const int col  = t & 7;
    const int slot = (row == 0) ? 0 : (row == 1) ? 2 : (row == 2) ? 1 : 3;
    const unsigned int idx = unpack_idx(ws[slot]);
    out[t] = res[(size_t)idx * 8 + col];
}

extern "C" void kernel_launch(void* const* d_in, const int* in_sizes, int n_in,
                              void* d_out, int out_size, void* d_ws, size_t ws_size,
                              hipStream_t stream) {
    const float* res = (const float*)d_in[0];
    const float4* v = (const float4*)d_in[0];
    const int N = in_sizes[0] / 8;
    const int M = N * 2;                      // number of float4s
    unsigned long long* ws = (unsigned long long*)d_ws;

    // ws[0..1]: per-class packed argmax (pass 1); ws[2..3]: post-NMS argmax (pass 2).
    hipMemsetAsync(d_ws, 0, 4 * sizeof(unsigned long long), stream);

    const int threads = 256;
    int blocks = (M + threads - 1) / threads;
    if (blocks > 2048) blocks = 2048;

    nms_pass1<<<blocks, threads, 0, stream>>>(v, M, ws);
    nms_pass2<<<blocks, threads, 0, stream>>>(res, v, M, ws);
    nms_write<<<1, 64, 0, stream>>>(res, ws, (float*)d_out);
}